// Round 10
// baseline (229.891 us; speedup 1.0000x reference)
//
#include <hip/hip_runtime.h>
#include <stdint.h>

#define N_ROWS 100000
#define NRB 6250  // row-blocks of 16 (16*6250 == 100000 exactly)
#define EPS 1e-6f

typedef float f32x4 __attribute__((ext_vector_type(4)));
typedef __bf16 bf16x8 __attribute__((ext_vector_type(8)));
typedef ushort u16x8 __attribute__((ext_vector_type(8)));

__device__ __forceinline__ ushort f2bf(float f) {
  union { float f; uint32_t u; } v; v.f = f;
  uint32_t u = v.u;
  return (ushort)((u + 0x7FFFu + ((u >> 16) & 1u)) >> 16);
}

// ---- W f32 -> bf16 fragment-linear rearrange ----
// Wf: frag = j16*16 + kt (kt = k/32); lane l holds W[j16*16+(l&15)][kt*32+(l>>4)*8 .. +8]
// frag stride = 512 ushorts (64 lanes x 8). Wave fragment load = 1KB coalesced.
__global__ __launch_bounds__(256) void wconv2_kernel(const float* __restrict__ W,
                                                     ushort* __restrict__ Wf) {
  int t = blockIdx.x * 256 + threadIdx.x;  // 0..32767
  int frag = t >> 6;
  int lane = t & 63;
  int j = (frag >> 4) * 16 + (lane & 15);
  int kb = (frag & 15) * 32 + (lane >> 4) * 8;
  const float* src = W + j * 512 + kb;
  float4 a = *(const float4*)src;
  float4 b = *(const float4*)(src + 4);
  ushort4 lo, hi;
  lo.x = f2bf(a.x); lo.y = f2bf(a.y); lo.z = f2bf(a.z); lo.w = f2bf(a.w);
  hi.x = f2bf(b.x); hi.y = f2bf(b.y); hi.z = f2bf(b.z); hi.w = f2bf(b.w);
  ushort* dst = Wf + (size_t)t * 8;
  *(ushort4*)dst = lo;
  *(ushort4*)(dst + 4) = hi;
}

// ---- pack: gather all 4 tables -> bf16 fragment-linear A ----
// Af: frag = rb*16 + kt; lane l holds A[rb*16+(l&15)][kt*32+(l>>4)*8 .. +8]
// at (frag*64 + l)*8 ushorts. One block per rowblock; wave w == table, does
// kt = w*4 .. w*4+3. Reads whole 512B source rows; writes 1KB coalesced.
__global__ __launch_bounds__(256) void pack_kernel(
    const float* __restrict__ f1, const float* __restrict__ f2,
    const float* __restrict__ f3, const float* __restrict__ f4,
    const int* __restrict__ i1, const int* __restrict__ i2,
    const int* __restrict__ i3, const int* __restrict__ i4,
    ushort* __restrict__ Af) {
  const int rb = blockIdx.x;
  const int t = threadIdx.x;
  const int w = t >> 6;   // wave == table
  const int l = t & 63;
  const int cl = l & 15;
  const int gq = l >> 4;
  const int row = rb * 16 + cl;  // < 100000 always
  const float* ft = (w == 0) ? f1 : (w == 1) ? f2 : (w == 2) ? f3 : f4;
  const int* it = (w == 0) ? i1 : (w == 1) ? i2 : (w == 2) ? i3 : i4;
  const float* src = ft + (size_t)it[row] * 128 + gq * 8;
  ushort* dst = Af + ((size_t)(rb * 16 + w * 4) * 64 + l) * 8;
#pragma unroll
  for (int i = 0; i < 4; ++i) {
    float4 a = *(const float4*)(src + i * 32);
    float4 b = *(const float4*)(src + i * 32 + 4);
    u16x8 o;
    o[0] = f2bf(a.x); o[1] = f2bf(a.y); o[2] = f2bf(a.z); o[3] = f2bf(a.w);
    o[4] = f2bf(b.x); o[5] = f2bf(b.y); o[6] = f2bf(b.z); o[7] = f2bf(b.w);
    *(u16x8*)(dst + i * 512) = o;
  }
}

// ---- GEMM + bias + relu + layernorm: m97-style async-B structure ----
// 512 threads = 8 waves (2M x 4N); tile 64 rows x 512 cols.
// wave w: wr=w>>2 rows [wr*32,+32), wc=w&3 cols [wc*128,+128).
// B kt-slice (32 KB) double-buffered in LDS via global_load_lds (async);
// A-frags direct global->VGPR from L3-hot Af, issued BEFORE the glds so the
// compiler's counted vmcnt leaves staging in flight. 2 blocks/CU cover drains.
__global__ __launch_bounds__(512, 4) void gemmln4_kernel(
    const ushort* __restrict__ Af, const ushort* __restrict__ Wf,
    const float* __restrict__ bias, const float* __restrict__ gamma,
    const float* __restrict__ beta, float* __restrict__ out) {
  __shared__ ushort Bl[2][32 * 512];  // 2 x 32 KB B double-buffer
  __shared__ float2 red[64 * 4];      // 2 KB LN cross-wave reduce

  const int t = threadIdx.x;
  const int w = t >> 6;
  const int l = t & 63;
  const int cl = l & 15;
  const int gq = l >> 4;
  const int wr = w >> 2;  // 0..1 row-half
  const int wc = w & 3;   // 0..3 col-quarter
  const int blk = blockIdx.x;  // rows [blk*64, +64)

  // A fragment bases (rowblock16 = blk*4 + wr*2 + rb, clamped; stride 8192)
  const ushort* Ap[2];
#pragma unroll
  for (int rb = 0; rb < 2; ++rb) {
    int r16 = blk * 4 + wr * 2 + rb;
    if (r16 > NRB - 1) r16 = NRB - 1;  // tail: dup rows, stores masked
    Ap[rb] = Af + (size_t)r16 * 8192 + (size_t)l * 8;
  }

  // B staging: issue q (0..3): frag f = q*8 + w; src Wf + (f*16+kt)*512 + l*8;
  // dest Bl[buf] + f*512 (wave-uniform) + lane*16B  == glds layout exactly.
  // prologue: stage kt=0 into buf 0
#pragma unroll
  for (int q = 0; q < 4; ++q) {
    const int f = q * 8 + w;
    const ushort* g = Wf + ((size_t)f * 16 + 0) * 512 + (size_t)l * 8;
    __builtin_amdgcn_global_load_lds(
        (const __attribute__((address_space(1))) void*)g,
        (__attribute__((address_space(3))) void*)(Bl[0] + f * 512), 16, 0, 0);
  }

  f32x4 acc[2][8];
#pragma unroll
  for (int rb = 0; rb < 2; ++rb)
#pragma unroll
    for (int n = 0; n < 8; ++n)
      acc[rb][n] = (f32x4){0.f, 0.f, 0.f, 0.f};

  __syncthreads();  // B0 staged

#pragma unroll
  for (int kt = 0; kt < 16; ++kt) {
    // (1) A-frags for this step: global->VGPR (L3-hot), FIRST in vmcnt order
    bf16x8 afr[2];
#pragma unroll
    for (int rb = 0; rb < 2; ++rb)
      afr[rb] = *(const bf16x8*)(Ap[rb] + (size_t)kt * 512);
    // (2) async-stage B for kt+1 into the other buffer
    if (kt < 15) {
#pragma unroll
      for (int q = 0; q < 4; ++q) {
        const int f = q * 8 + w;
        const ushort* g = Wf + ((size_t)f * 16 + kt + 1) * 512 + (size_t)l * 8;
        __builtin_amdgcn_global_load_lds(
            (const __attribute__((address_space(1))) void*)g,
            (__attribute__((address_space(3))) void*)(Bl[(kt + 1) & 1] + f * 512),
            16, 0, 0);
      }
    }
    // (3) B-frags from LDS (1KB contiguous per wave -> conflict-free)
    bf16x8 bfr[8];
#pragma unroll
    for (int n = 0; n < 8; ++n)
      bfr[n] = *(const bf16x8*)(Bl[kt & 1] + (wc * 8 + n) * 512 + l * 8);
    // (4) 16 MFMA
#pragma unroll
    for (int n = 0; n < 8; ++n)
#pragma unroll
      for (int rb = 0; rb < 2; ++rb)
        acc[rb][n] = __builtin_amdgcn_mfma_f32_16x16x32_bf16(
            afr[rb], bfr[n], acc[rb][n], 0, 0, 0);
    // (5) barrier: drains glds (needed for kt+1) + guards buffer reuse
    __syncthreads();
  }

  // ---- epilogue: bias + relu + layernorm(512) ----
  const int wcol = wc * 128;
  float bia[8], gam[8], bet[8];
#pragma unroll
  for (int n = 0; n < 8; ++n) {
    int col = wcol + n * 16 + cl;
    bia[n] = bias[col];
    gam[n] = gamma[col];
    bet[n] = beta[col];
  }

#pragma unroll
  for (int rb = 0; rb < 2; ++rb) {
#pragma unroll
    for (int r = 0; r < 4; ++r) {
      float s = 0.f, ss = 0.f;
#pragma unroll
      for (int n = 0; n < 8; ++n) {
        float v = acc[rb][n][r] + bia[n];
        v = fmaxf(v, 0.f);
        acc[rb][n][r] = v;
        s += v;
        ss += v * v;
      }
#pragma unroll
      for (int m = 1; m < 16; m <<= 1) {
        s += __shfl_xor(s, m);
        ss += __shfl_xor(ss, m);
      }
      if (cl == 0) {
        int row = wr * 32 + rb * 16 + gq * 4 + r;  // 0..63
        red[row * 4 + wc] = make_float2(s, ss);
      }
    }
  }
  __syncthreads();

#pragma unroll
  for (int rb = 0; rb < 2; ++rb) {
#pragma unroll
    for (int r = 0; r < 4; ++r) {
      int row = wr * 32 + rb * 16 + gq * 4 + r;
      float S = 0.f, SS = 0.f;
#pragma unroll
      for (int wv = 0; wv < 4; ++wv) {
        float2 p = red[row * 4 + wv];
        S += p.x;
        SS += p.y;
      }
      float mu = S * (1.f / 512.f);
      float var = SS * (1.f / 512.f) - mu * mu;
      float rstd = rsqrtf(var + EPS);
      int g = blk * 64 + row;
      if (g < N_ROWS) {
        float* orow = out + (size_t)g * 512 + wcol;
#pragma unroll
        for (int n = 0; n < 8; ++n)
          orow[n * 16 + cl] = (acc[rb][n][r] - mu) * rstd * gam[n] + bet[n];
      }
    }
  }
}

// ================= fallback (R2 kernel) if ws_size too small =================
__global__ __launch_bounds__(512, 4) void fused2_kernel(
    const float* __restrict__ f1, const float* __restrict__ f2,
    const float* __restrict__ f3, const float* __restrict__ f4,
    const int* __restrict__ i1, const int* __restrict__ i2,
    const int* __restrict__ i3, const int* __restrict__ i4,
    const ushort* __restrict__ Wf, const float* __restrict__ bias,
    const float* __restrict__ gamma, const float* __restrict__ beta,
    float* __restrict__ out) {
  __shared__ ushort Al[2][64 * 32];
  __shared__ float2 red[64 * 8];

  const int t = threadIdx.x;
  const int w = t >> 6;
  const int l = t & 63;
  const int cl = l & 15;
  const int gq = l >> 4;
  const int blk = blockIdx.x;

  const int arow = t >> 3;
  const int e8 = t & 7;
  int gi = blk * 64 + arow;
  int gic = gi < N_ROWS ? gi : (N_ROWS - 1);
  const float* ap0 = f1 + (size_t)i1[gic] * 128 + e8 * 4;
  const float* ap1 = f2 + (size_t)i2[gic] * 128 + e8 * 4;
  const float* ap2 = f3 + (size_t)i3[gic] * 128 + e8 * 4;
  const float* ap3 = f4 + (size_t)i4[gic] * 128 + e8 * 4;
  const int achunk = (e8 >> 1) ^ ((arow >> 1) & 3);
  const int awoff = arow * 32 + achunk * 8 + (e8 & 1) * 4;
  const int roff = cl * 32 + ((gq ^ ((cl >> 1) & 3)) * 8);
  const ushort* Bbase = Wf + (size_t)w * 4 * 8192 + (size_t)l * 8;

  f32x4 acc[4][4];
#pragma unroll
  for (int rb = 0; rb < 4; ++rb)
#pragma unroll
    for (int cb = 0; cb < 4; ++cb)
      acc[rb][cb] = (f32x4){0.f, 0.f, 0.f, 0.f};

  {
    float4 av = *(const float4*)ap0;
    ushort4 ab;
    ab.x = f2bf(av.x); ab.y = f2bf(av.y); ab.z = f2bf(av.z); ab.w = f2bf(av.w);
    *(ushort4*)(Al[0] + awoff) = ab;
  }
  __syncthreads();

#pragma unroll
  for (int kt = 0; kt < 16; ++kt) {
    const int cur = kt & 1;
    float4 av;
    if (kt < 15) {
      const int t2 = (kt + 1) >> 2;
      const int k2 = (kt + 1) & 3;
      const float* ap = (t2 == 0) ? ap0 : (t2 == 1) ? ap1 : (t2 == 2) ? ap2 : ap3;
      av = *(const float4*)(ap + k2 * 32);
    }
    bf16x8 bfr[4];
#pragma unroll
    for (int cb = 0; cb < 4; ++cb)
      bfr[cb] = *(const bf16x8*)(Bbase + cb * 8192 + kt * 512);
    bf16x8 af[4];
#pragma unroll
    for (int rb = 0; rb < 4; ++rb)
      af[rb] = *(const bf16x8*)(Al[cur] + rb * 512 + roff);
#pragma unroll
    for (int cb = 0; cb < 4; ++cb)
#pragma unroll
      for (int rb = 0; rb < 4; ++rb)
        acc[rb][cb] = __builtin_amdgcn_mfma_f32_16x16x32_bf16(
            af[rb], bfr[cb], acc[rb][cb], 0, 0, 0);
    if (kt < 15) {
      ushort4 ab;
      ab.x = f2bf(av.x); ab.y = f2bf(av.y); ab.z = f2bf(av.z); ab.w = f2bf(av.w);
      *(ushort4*)(Al[cur ^ 1] + awoff) = ab;
    }
    __syncthreads();
  }

  const int wcol = w * 64;
  float bia[4], gam[4], bet[4];
#pragma unroll
  for (int cb = 0; cb < 4; ++cb) {
    int col = wcol + cb * 16 + cl;
    bia[cb] = bias[col];
    gam[cb] = gamma[col];
    bet[cb] = beta[col];
  }

#pragma unroll
  for (int rb = 0; rb < 4; ++rb) {
#pragma unroll
    for (int r = 0; r < 4; ++r) {
      float s = 0.f, ss = 0.f;
#pragma unroll
      for (int cb = 0; cb < 4; ++cb) {
        float v = acc[rb][cb][r] + bia[cb];
        v = fmaxf(v, 0.f);
        acc[rb][cb][r] = v;
        s += v;
        ss += v * v;
      }
#pragma unroll
      for (int m = 1; m < 16; m <<= 1) {
        s += __shfl_xor(s, m);
        ss += __shfl_xor(ss, m);
      }
      if (cl == 0) {
        int row = rb * 16 + gq * 4 + r;
        red[row * 8 + w] = make_float2(s, ss);
      }
    }
  }
  __syncthreads();

#pragma unroll
  for (int rb = 0; rb < 4; ++rb) {
#pragma unroll
    for (int r = 0; r < 4; ++r) {
      int row = rb * 16 + gq * 4 + r;
      float S = 0.f, SS = 0.f;
#pragma unroll
      for (int wv = 0; wv < 8; ++wv) {
        float2 p = red[row * 8 + wv];
        S += p.x;
        SS += p.y;
      }
      float mu = S * (1.f / 512.f);
      float var = SS * (1.f / 512.f) - mu * mu;
      float rstd = rsqrtf(var + EPS);
      int g = blk * 64 + row;
      if (g < N_ROWS) {
        float* orow = out + (size_t)g * 512 + wcol;
#pragma unroll
        for (int cb = 0; cb < 4; ++cb)
          orow[cb * 16 + cl] = (acc[rb][cb][r] - mu) * rstd * gam[cb] + bet[cb];
      }
    }
  }
}

extern "C" void kernel_launch(void* const* d_in, const int* in_sizes, int n_in,
                              void* d_out, int out_size, void* d_ws, size_t ws_size,
                              hipStream_t stream) {
  const float* f1 = (const float*)d_in[0];
  const int* i1 = (const int*)d_in[1];
  const float* f2 = (const float*)d_in[2];
  const int* i2 = (const int*)d_in[3];
  const float* f3 = (const float*)d_in[4];
  const int* i3 = (const int*)d_in[5];
  const float* f4 = (const float*)d_in[6];
  const int* i4 = (const int*)d_in[7];
  const float* W = (const float*)d_in[8];
  const float* b = (const float*)d_in[9];
  const float* gm = (const float*)d_in[10];
  const float* bt = (const float*)d_in[11];
  float* out = (float*)d_out;

  ushort* Wf = (ushort*)d_ws;                       // 512 KB fragment-linear W
  const size_t WF_BYTES = 524288;
  const size_t AF_BYTES = (size_t)NRB * 16 * 64 * 8 * 2;  // 102.4 MB
  ushort* Af = (ushort*)((char*)d_ws + WF_BYTES);

  wconv2_kernel<<<128, 256, 0, stream>>>(W, Wf);
  if (ws_size >= WF_BYTES + AF_BYTES) {
    pack_kernel<<<NRB, 256, 0, stream>>>(f1, f2, f3, f4, i1, i2, i3, i4, Af);
    gemmln4_kernel<<<(N_ROWS + 63) / 64, 512, 0, stream>>>(Af, Wf, b, gm, bt, out);
  } else {
    fused2_kernel<<<(N_ROWS + 63) / 64, 512, 0, stream>>>(
        f1, f2, f3, f4, i1, i2, i3, i4, Wf, b, gm, bt, out);
  }
}

// Round 11
// 183.748 us; speedup vs baseline: 1.2511x; 1.2511x over previous
//
#include <hip/hip_runtime.h>
#include <stdint.h>

#define N_ROWS 100000
#define NRB 6250  // row-blocks of 16 (16*6250 == 100000 exactly)
#define EPS 1e-6f

typedef float f32x4 __attribute__((ext_vector_type(4)));
typedef __bf16 bf16x8 __attribute__((ext_vector_type(8)));
typedef ushort u16x8 __attribute__((ext_vector_type(8)));

__device__ __forceinline__ ushort f2bf(float f) {
  union { float f; uint32_t u; } v; v.f = f;
  uint32_t u = v.u;
  return (ushort)((u + 0x7FFFu + ((u >> 16) & 1u)) >> 16);
}

// ---- W f32 -> bf16 fragment-linear rearrange ----
// Wf: frag = j16*16 + kt (kt = k/32); lane l holds W[j16*16+(l&15)][kt*32+(l>>4)*8 .. +8]
// frag stride = 512 ushorts (64 lanes x 8). Wave fragment load = 1KB coalesced.
__global__ __launch_bounds__(256) void wconv2_kernel(const float* __restrict__ W,
                                                     ushort* __restrict__ Wf) {
  int t = blockIdx.x * 256 + threadIdx.x;  // 0..32767
  int frag = t >> 6;
  int lane = t & 63;
  int j = (frag >> 4) * 16 + (lane & 15);
  int kb = (frag & 15) * 32 + (lane >> 4) * 8;
  const float* src = W + j * 512 + kb;
  float4 a = *(const float4*)src;
  float4 b = *(const float4*)(src + 4);
  ushort4 lo, hi;
  lo.x = f2bf(a.x); lo.y = f2bf(a.y); lo.z = f2bf(a.z); lo.w = f2bf(a.w);
  hi.x = f2bf(b.x); hi.y = f2bf(b.y); hi.z = f2bf(b.z); hi.w = f2bf(b.w);
  ushort* dst = Wf + (size_t)t * 8;
  *(ushort4*)dst = lo;
  *(ushort4*)(dst + 4) = hi;
}

// ---- pack: gather all 4 tables -> bf16 fragment-linear A ----
// Af: frag = rb*16 + kt; lane l holds A[rb*16+(l&15)][kt*32+(l>>4)*8 .. +8]
// at (frag*64 + l)*8 ushorts. One block per rowblock; wave w == table, does
// kt = w*4 .. w*4+3. Reads whole 512B source rows; writes 1KB coalesced.
__global__ __launch_bounds__(256) void pack_kernel(
    const float* __restrict__ f1, const float* __restrict__ f2,
    const float* __restrict__ f3, const float* __restrict__ f4,
    const int* __restrict__ i1, const int* __restrict__ i2,
    const int* __restrict__ i3, const int* __restrict__ i4,
    ushort* __restrict__ Af) {
  const int rb = blockIdx.x;
  const int t = threadIdx.x;
  const int w = t >> 6;   // wave == table
  const int l = t & 63;
  const int cl = l & 15;
  const int gq = l >> 4;
  const int row = rb * 16 + cl;  // < 100000 always
  const float* ft = (w == 0) ? f1 : (w == 1) ? f2 : (w == 2) ? f3 : f4;
  const int* it = (w == 0) ? i1 : (w == 1) ? i2 : (w == 2) ? i3 : i4;
  const float* src = ft + (size_t)it[row] * 128 + gq * 8;
  ushort* dst = Af + ((size_t)(rb * 16 + w * 4) * 64 + l) * 8;
#pragma unroll
  for (int i = 0; i < 4; ++i) {
    float4 a = *(const float4*)(src + i * 32);
    float4 b = *(const float4*)(src + i * 32 + 4);
    u16x8 o;
    o[0] = f2bf(a.x); o[1] = f2bf(a.y); o[2] = f2bf(a.z); o[3] = f2bf(a.w);
    o[4] = f2bf(b.x); o[5] = f2bf(b.y); o[6] = f2bf(b.z); o[7] = f2bf(b.w);
    *(u16x8*)(dst + i * 512) = o;
  }
}

// ---- GEMM + bias + relu + layernorm: WAVE-PRIVATE barrier-free pipelines ----
// 256 threads = 4 waves; tile 32 rows x 512 cols (3125 blocks, no tail).
// Each wave owns a PRIVATE 10KB LDS slice: 2 A-frags + its 8 B-frags per kt,
// staged via global_load_lds and consumed after the wave's OWN vmcnt(0) --
// NO barriers in the K-loop, waves slip freely (pure TLP latency hiding).
// 41KB LDS + VGPR<=~170 -> 3 blocks/CU = 3 independent pipelines per SIMD.
__global__ __launch_bounds__(256, 3) void gemmln5_kernel(
    const ushort* __restrict__ Af, const ushort* __restrict__ Wf,
    const float* __restrict__ bias, const float* __restrict__ gamma,
    const float* __restrict__ beta, float* __restrict__ out) {
  __shared__ ushort S[4][10 * 512];  // per-wave slice: [0..1]=A frags, [2..9]=B frags
  __shared__ float2 red[32 * 4];     // 1 KB LN cross-wave reduce

  const int t = threadIdx.x;
  const int w = t >> 6;   // wave 0..3 == col quarter
  const int l = t & 63;
  const int cl = l & 15;
  const int gq = l >> 4;
  const int blk = blockIdx.x;  // rows [blk*32, +32), 3125 blocks exact

  ushort* sl = &S[w][0];

  // A fragment sources: rowblock16 r16 = blk*2 + rb; frag (r16*16 + kt)
  const ushort* Asrc = Af + (size_t)(blk * 2) * 8192 + (size_t)l * 8;
  // B fragment sources: frag f = w*8 + n at (f*16 + kt)*512
  const ushort* Bsrc = Wf + (size_t)(w * 8) * 8192 + (size_t)l * 8;

  f32x4 acc[2][8];
#pragma unroll
  for (int rb = 0; rb < 2; ++rb)
#pragma unroll
    for (int n = 0; n < 8; ++n)
      acc[rb][n] = (f32x4){0.f, 0.f, 0.f, 0.f};

#pragma unroll
  for (int kt = 0; kt < 16; ++kt) {
    // (1) stage this wave's 10 fragments into its private slice (async)
#pragma unroll
    for (int rb = 0; rb < 2; ++rb) {
      const ushort* g = Asrc + ((size_t)rb * 16 + kt) * 512;
      __builtin_amdgcn_global_load_lds(
          (const __attribute__((address_space(1))) void*)g,
          (__attribute__((address_space(3))) void*)(sl + rb * 512), 16, 0, 0);
    }
#pragma unroll
    for (int n = 0; n < 8; ++n) {
      const ushort* g = Bsrc + ((size_t)n * 16 + kt) * 512;
      __builtin_amdgcn_global_load_lds(
          (const __attribute__((address_space(1))) void*)g,
          (__attribute__((address_space(3))) void*)(sl + (2 + n) * 512), 16, 0, 0);
    }
    // (2) wait for OUR loads only (per-wave vmcnt) -- no barrier
    asm volatile("s_waitcnt vmcnt(0)" ::: "memory");
    __builtin_amdgcn_sched_barrier(0);
    // (3) read fragments from private slice
    bf16x8 afr[2], bfr[8];
#pragma unroll
    for (int rb = 0; rb < 2; ++rb)
      afr[rb] = *(const bf16x8*)(sl + rb * 512 + l * 8);
#pragma unroll
    for (int n = 0; n < 8; ++n)
      bfr[n] = *(const bf16x8*)(sl + (2 + n) * 512 + l * 8);
    // (4) 16 MFMA
#pragma unroll
    for (int n = 0; n < 8; ++n)
#pragma unroll
      for (int rb = 0; rb < 2; ++rb)
        acc[rb][n] = __builtin_amdgcn_mfma_f32_16x16x32_bf16(
            afr[rb], bfr[n], acc[rb][n], 0, 0, 0);
    // (5) ensure our ds_reads retired before next kt overwrites the slice
    asm volatile("s_waitcnt lgkmcnt(0)" ::: "memory");
    __builtin_amdgcn_sched_barrier(0);
  }

  // ---- epilogue: bias + relu + layernorm(512) ----
  const int wcol = w * 128;
  float bia[8], gam[8], bet[8];
#pragma unroll
  for (int n = 0; n < 8; ++n) {
    int col = wcol + n * 16 + cl;
    bia[n] = bias[col];
    gam[n] = gamma[col];
    bet[n] = beta[col];
  }

#pragma unroll
  for (int rb = 0; rb < 2; ++rb) {
#pragma unroll
    for (int r = 0; r < 4; ++r) {
      float s = 0.f, ss = 0.f;
#pragma unroll
      for (int n = 0; n < 8; ++n) {
        float v = acc[rb][n][r] + bia[n];
        v = fmaxf(v, 0.f);
        acc[rb][n][r] = v;
        s += v;
        ss += v * v;
      }
#pragma unroll
      for (int m = 1; m < 16; m <<= 1) {
        s += __shfl_xor(s, m);
        ss += __shfl_xor(ss, m);
      }
      if (cl == 0) {
        int row = rb * 16 + gq * 4 + r;  // 0..31
        red[row * 4 + w] = make_float2(s, ss);
      }
    }
  }
  __syncthreads();  // the ONLY block-wide barrier

#pragma unroll
  for (int rb = 0; rb < 2; ++rb) {
#pragma unroll
    for (int r = 0; r < 4; ++r) {
      int row = rb * 16 + gq * 4 + r;
      float S0 = 0.f, SS = 0.f;
#pragma unroll
      for (int wv = 0; wv < 4; ++wv) {
        float2 p = red[row * 4 + wv];
        S0 += p.x;
        SS += p.y;
      }
      float mu = S0 * (1.f / 512.f);
      float var = SS * (1.f / 512.f) - mu * mu;
      float rstd = rsqrtf(var + EPS);
      float* orow = out + (size_t)(blk * 32 + row) * 512 + wcol;
#pragma unroll
      for (int n = 0; n < 8; ++n)
        orow[n * 16 + cl] = (acc[rb][n][r] - mu) * rstd * gam[n] + bet[n];
    }
  }
}

// ================= fallback (R2 kernel) if ws_size too small =================
__global__ __launch_bounds__(512, 4) void fused2_kernel(
    const float* __restrict__ f1, const float* __restrict__ f2,
    const float* __restrict__ f3, const float* __restrict__ f4,
    const int* __restrict__ i1, const int* __restrict__ i2,
    const int* __restrict__ i3, const int* __restrict__ i4,
    const ushort* __restrict__ Wf, const float* __restrict__ bias,
    const float* __restrict__ gamma, const float* __restrict__ beta,
    float* __restrict__ out) {
  __shared__ ushort Al[2][64 * 32];
  __shared__ float2 red[64 * 8];

  const int t = threadIdx.x;
  const int w = t >> 6;
  const int l = t & 63;
  const int cl = l & 15;
  const int gq = l >> 4;
  const int blk = blockIdx.x;

  const int arow = t >> 3;
  const int e8 = t & 7;
  int gi = blk * 64 + arow;
  int gic = gi < N_ROWS ? gi : (N_ROWS - 1);
  const float* ap0 = f1 + (size_t)i1[gic] * 128 + e8 * 4;
  const float* ap1 = f2 + (size_t)i2[gic] * 128 + e8 * 4;
  const float* ap2 = f3 + (size_t)i3[gic] * 128 + e8 * 4;
  const float* ap3 = f4 + (size_t)i4[gic] * 128 + e8 * 4;
  const int achunk = (e8 >> 1) ^ ((arow >> 1) & 3);
  const int awoff = arow * 32 + achunk * 8 + (e8 & 1) * 4;
  const int roff = cl * 32 + ((gq ^ ((cl >> 1) & 3)) * 8);
  const ushort* Bbase = Wf + (size_t)w * 4 * 8192 + (size_t)l * 8;

  f32x4 acc[4][4];
#pragma unroll
  for (int rb = 0; rb < 4; ++rb)
#pragma unroll
    for (int cb = 0; cb < 4; ++cb)
      acc[rb][cb] = (f32x4){0.f, 0.f, 0.f, 0.f};

  {
    float4 av = *(const float4*)ap0;
    ushort4 ab;
    ab.x = f2bf(av.x); ab.y = f2bf(av.y); ab.z = f2bf(av.z); ab.w = f2bf(av.w);
    *(ushort4*)(Al[0] + awoff) = ab;
  }
  __syncthreads();

#pragma unroll
  for (int kt = 0; kt < 16; ++kt) {
    const int cur = kt & 1;
    float4 av;
    if (kt < 15) {
      const int t2 = (kt + 1) >> 2;
      const int k2 = (kt + 1) & 3;
      const float* ap = (t2 == 0) ? ap0 : (t2 == 1) ? ap1 : (t2 == 2) ? ap2 : ap3;
      av = *(const float4*)(ap + k2 * 32);
    }
    bf16x8 bfr[4];
#pragma unroll
    for (int cb = 0; cb < 4; ++cb)
      bfr[cb] = *(const bf16x8*)(Bbase + cb * 8192 + kt * 512);
    bf16x8 af[4];
#pragma unroll
    for (int rb = 0; rb < 4; ++rb)
      af[rb] = *(const bf16x8*)(Al[cur] + rb * 512 + roff);
#pragma unroll
    for (int cb = 0; cb < 4; ++cb)
#pragma unroll
      for (int rb = 0; rb < 4; ++rb)
        acc[rb][cb] = __builtin_amdgcn_mfma_f32_16x16x32_bf16(
            af[rb], bfr[cb], acc[rb][cb], 0, 0, 0);
    if (kt < 15) {
      ushort4 ab;
      ab.x = f2bf(av.x); ab.y = f2bf(av.y); ab.z = f2bf(av.z); ab.w = f2bf(av.w);
      *(ushort4*)(Al[cur ^ 1] + awoff) = ab;
    }
    __syncthreads();
  }

  const int wcol = w * 64;
  float bia[4], gam[4], bet[4];
#pragma unroll
  for (int cb = 0; cb < 4; ++cb) {
    int col = wcol + cb * 16 + cl;
    bia[cb] = bias[col];
    gam[cb] = gamma[col];
    bet[cb] = beta[col];
  }

#pragma unroll
  for (int rb = 0; rb < 4; ++rb) {
#pragma unroll
    for (int r = 0; r < 4; ++r) {
      float s = 0.f, ss = 0.f;
#pragma unroll
      for (int cb = 0; cb < 4; ++cb) {
        float v = acc[rb][cb][r] + bia[cb];
        v = fmaxf(v, 0.f);
        acc[rb][cb][r] = v;
        s += v;
        ss += v * v;
      }
#pragma unroll
      for (int m = 1; m < 16; m <<= 1) {
        s += __shfl_xor(s, m);
        ss += __shfl_xor(ss, m);
      }
      if (cl == 0) {
        int row = rb * 16 + gq * 4 + r;
        red[row * 8 + w] = make_float2(s, ss);
      }
    }
  }
  __syncthreads();

#pragma unroll
  for (int rb = 0; rb < 4; ++rb) {
#pragma unroll
    for (int r = 0; r < 4; ++r) {
      int row = rb * 16 + gq * 4 + r;
      float S = 0.f, SS = 0.f;
#pragma unroll
      for (int wv = 0; wv < 8; ++wv) {
        float2 p = red[row * 8 + wv];
        S += p.x;
        SS += p.y;
      }
      float mu = S * (1.f / 512.f);
      float var = SS * (1.f / 512.f) - mu * mu;
      float rstd = rsqrtf(var + EPS);
      int g = blk * 64 + row;
      if (g < N_ROWS) {
        float* orow = out + (size_t)g * 512 + wcol;
#pragma unroll
        for (int cb = 0; cb < 4; ++cb)
          orow[cb * 16 + cl] = (acc[rb][cb][r] - mu) * rstd * gam[cb] + bet[cb];
      }
    }
  }
}

extern "C" void kernel_launch(void* const* d_in, const int* in_sizes, int n_in,
                              void* d_out, int out_size, void* d_ws, size_t ws_size,
                              hipStream_t stream) {
  const float* f1 = (const float*)d_in[0];
  const int* i1 = (const int*)d_in[1];
  const float* f2 = (const float*)d_in[2];
  const int* i2 = (const int*)d_in[3];
  const float* f3 = (const float*)d_in[4];
  const int* i3 = (const int*)d_in[5];
  const float* f4 = (const float*)d_in[6];
  const int* i4 = (const int*)d_in[7];
  const float* W = (const float*)d_in[8];
  const float* b = (const float*)d_in[9];
  const float* gm = (const float*)d_in[10];
  const float* bt = (const float*)d_in[11];
  float* out = (float*)d_out;

  ushort* Wf = (ushort*)d_ws;                       // 512 KB fragment-linear W
  const size_t WF_BYTES = 524288;
  const size_t AF_BYTES = (size_t)NRB * 16 * 64 * 8 * 2;  // 102.4 MB
  ushort* Af = (ushort*)((char*)d_ws + WF_BYTES);

  wconv2_kernel<<<128, 256, 0, stream>>>(W, Wf);
  if (ws_size >= WF_BYTES + AF_BYTES) {
    pack_kernel<<<NRB, 256, 0, stream>>>(f1, f2, f3, f4, i1, i2, i3, i4, Af);
    gemmln5_kernel<<<N_ROWS / 32, 256, 0, stream>>>(Af, Wf, b, gm, bt, out);
  } else {
    fused2_kernel<<<(N_ROWS + 63) / 64, 512, 0, stream>>>(
        f1, f2, f3, f4, i1, i2, i3, i4, Wf, b, gm, bt, out);
  }
}